// Round 14
// baseline (482.798 us; speedup 1.0000x reference)
//
#include <hip/hip_runtime.h>
#include <hip/hip_bf16.h>

#define T_SEQ 1024
#define D_MODEL 768
#define QKVW 2304
#define NHEAD 12
#define NLAYER 2
#define MCOPY 2
#define HID_DIM 3072
#define VSIZE 32000
#define NCH 32
#define TL 32

typedef __attribute__((ext_vector_type(8))) short short8;
typedef __attribute__((ext_vector_type(4))) float f32x4;

__device__ __forceinline__ short f2bf(float f) {
  unsigned u = __builtin_bit_cast(unsigned, f);
  u = (u + 0x7FFFu + ((u >> 16) & 1u)) >> 16;   // RNE
  return (short)u;
}

// ---------------- sin/cos table: stc[t][i] = (cos, sin) ----------------
__global__ __launch_bounds__(64) void stc_k(float* __restrict__ stc) {
  int t = blockIdx.x;
  int i = threadIdx.x;
  if (i < 32) {
    float theta = powf(10000.0f, -(float)i / 32.0f);
    float s, c;
    sincosf((float)t * theta, &s, &c);
    stc[t * 64 + 2 * i] = c;
    stc[t * 64 + 2 * i + 1] = s;
  }
}

// -------- fused embedding gather + rmsnorm -> X (f32) and HbB (bf16) -------
__global__ __launch_bounds__(256) void embed_norm_k(const int* __restrict__ idx,
                                                    const float* __restrict__ emb,
                                                    const float* __restrict__ w,
                                                    float* __restrict__ x,
                                                    short* __restrict__ out) {
  int t = blockIdx.x, tid = threadIdx.x;
  int r = idx[t];
  float v[3];
  float ss = 0.f;
  #pragma unroll
  for (int j = 0; j < 3; ++j) {
    int i = tid + j * 256;
    float val = emb[(size_t)r * D_MODEL + i];
    x[(size_t)t * D_MODEL + i] = val;
    v[j] = val;
    ss += val * val;
  }
  __shared__ float red[256];
  red[tid] = ss; __syncthreads();
  for (int s = 128; s > 0; s >>= 1) {
    if (tid < s) red[tid] += red[tid + s];
    __syncthreads();
  }
  float inv = rsqrtf(red[0] / (float)D_MODEL + 1e-5f);
  #pragma unroll
  for (int j = 0; j < 3; ++j) {
    int i = tid + j * 256;
    out[(size_t)t * D_MODEL + i] = f2bf(v[j] * inv * w[i]);
  }
}

// ------- fused: X += sum(parts) (+bias); out = rmsnorm(X)*w -> bf16 -------
__global__ __launch_bounds__(256) void add_norm_k(float* __restrict__ x,
                                                  const float* __restrict__ parts,
                                                  int nparts,
                                                  const float* __restrict__ bias,
                                                  const float* __restrict__ w,
                                                  short* __restrict__ out) {
  int t = blockIdx.x, tid = threadIdx.x;
  float v[3];
  float ss = 0.f;
  #pragma unroll
  for (int j = 0; j < 3; ++j) {
    int i = tid + j * 256;
    float val = x[(size_t)t * D_MODEL + i];
    if (bias) val += bias[i];
    for (int p = 0; p < nparts; ++p)
      val += parts[(size_t)p * (T_SEQ * D_MODEL) + (size_t)t * D_MODEL + i];
    v[j] = val;
    ss += val * val;
  }
  __shared__ float red[256];
  red[tid] = ss; __syncthreads();
  for (int s = 128; s > 0; s >>= 1) {
    if (tid < s) red[tid] += red[tid + s];
    __syncthreads();
  }
  float inv = rsqrtf(red[0] / (float)D_MODEL + 1e-5f);
  #pragma unroll
  for (int j = 0; j < 3; ++j) {
    int i = tid + j * 256;
    if (nparts || bias) x[(size_t)t * D_MODEL + i] = v[j];
    out[(size_t)t * D_MODEL + i] = f2bf(v[j] * inv * w[i]);
  }
}

// ------------- batched weight transposes (f32 [K][N] -> bf16 [N][K]) -------
__device__ __forceinline__ void tr_tile(const float* __restrict__ W,
                                        short* __restrict__ WT, int K, int N,
                                        int n0, int k0, int tx, int ty) {
  __shared__ float tile[32][33];
  #pragma unroll
  for (int i = 0; i < 4; ++i)
    tile[ty + 8 * i][tx] = W[(size_t)(k0 + ty + 8 * i) * N + n0 + tx];
  __syncthreads();
  #pragma unroll
  for (int i = 0; i < 4; ++i)
    WT[(size_t)(n0 + ty + 8 * i) * K + k0 + tx] = f2bf(tile[tx][ty + 8 * i]);
}

#define SQ_W  ((size_t)D_MODEL * D_MODEL)
#define FF_W  ((size_t)D_MODEL * HID_DIM)
#define LAYER_W (4 * SQ_W + 3 * FF_W)

__global__ __launch_bounds__(256) void transpose_sq8(const float* __restrict__ qw,
                                                     const float* __restrict__ kw,
                                                     const float* __restrict__ vw,
                                                     const float* __restrict__ ow,
                                                     short* __restrict__ WB) {
  int z = blockIdx.z, layer = z >> 2, which = z & 3;
  const float* W = (which == 0) ? qw : (which == 1) ? kw : (which == 2) ? vw : ow;
  W += (size_t)layer * SQ_W;
  short* WT = WB + (size_t)layer * LAYER_W + (size_t)which * SQ_W;
  tr_tile(W, WT, D_MODEL, D_MODEL, blockIdx.x * 32, blockIdx.y * 32,
          threadIdx.x, threadIdx.y);
}

__global__ __launch_bounds__(256) void transpose_ff12(const float* __restrict__ W1g,
                                                      const float* __restrict__ W2g,
                                                      short* __restrict__ WB) {
  __shared__ float tile[32][33];
  int layer = blockIdx.z;
  const float* W1 = W1g + (size_t)layer * FF_W;
  const float* W2 = W2g + (size_t)layer * FF_W;
  short* WT = WB + (size_t)layer * LAYER_W + 4 * SQ_W;
  int tx = threadIdx.x, ty = threadIdx.y;
  int n0 = blockIdx.x * 32, k0 = blockIdx.y * 32;
  int h0 = n0 >> 1;
  const float* src = (tx < 16) ? (W1 + h0 + tx) : (W2 + h0 + (tx - 16));
  #pragma unroll
  for (int i = 0; i < 4; ++i)
    tile[ty + 8 * i][tx] = src[(size_t)(k0 + ty + 8 * i) * HID_DIM];
  __syncthreads();
  #pragma unroll
  for (int i = 0; i < 4; ++i) {
    int n = ty + 8 * i;
    WT[(size_t)(n0 + n) * D_MODEL + k0 + tx] = f2bf(tile[tx][n]);
  }
}

__global__ __launch_bounds__(256) void transpose_f3(const float* __restrict__ W3g,
                                                    short* __restrict__ WB) {
  int layer = blockIdx.z;
  const float* W = W3g + (size_t)layer * FF_W;
  short* WT = WB + (size_t)layer * LAYER_W + 4 * SQ_W + 2 * FF_W;
  tr_tile(W, WT, HID_DIM, D_MODEL, blockIdx.x * 32, blockIdx.y * 32,
          threadIdx.x, threadIdx.y);
}

__global__ __launch_bounds__(256) void transpose_head(const float* __restrict__ W,
                                                      short* __restrict__ WT) {
  tr_tile(W, WT, D_MODEL, VSIZE, blockIdx.x * 32, blockIdx.y * 32,
          threadIdx.x, threadIdx.y);
}

// ---------------- staging helper: NROW32*32 rows x 64 k (bf16) -------------
template<int NROW32>
__device__ __forceinline__ void stage_rows(const short* __restrict__ gbase,
                                           int ldK, short* lds, int tid) {
  #pragma unroll
  for (int j = 0; j < NROW32; ++j) {
    int r = j * 32 + (tid >> 3);
    int s = tid & 7;
    const short* gp = gbase + (size_t)r * ldK + (((s ^ (r & 7))) << 3);
    short* lp = lds + j * 2048 + tid * 8;
    __builtin_amdgcn_global_load_lds((const __attribute__((address_space(1))) void*)gp,
                                     (__attribute__((address_space(3))) void*)lp,
                                     16, 0, 0);
  }
}

__device__ __forceinline__ short8 frag_ld(const short* lds, int row, int sl) {
  return *(const short8*)(lds + row * 64 + ((sl ^ (row & 7)) << 3));
}

// ------ gemm64: 64x128 tile, dbuf; MODE 0/1 f32 out, MODE 2 silu-bf16 ------
// 4 waves, each 64 rows x 32 cols (af[4], bf[2], 8 MFMA/kk). 48 KB LDS,
// 3 blocks/CU. Used for ALL GEMMs incl. head (N=32000 -> 4000 blocks).
template<int MODE>
__global__ __launch_bounds__(256) void gemm64(const short* __restrict__ A,
                                              const short* __restrict__ Bt,
                                              float* __restrict__ Cf,
                                              short* __restrict__ Cs,
                                              int N, int K) {
  __shared__ short As[2][64 * 64];
  __shared__ short Bs[2][128 * 64];
  int tid = threadIdx.x;
  int lane = tid & 63;
  int wave = tid >> 6;            // col section
  int l15 = lane & 15, kg = lane >> 4;

  int cpx = gridDim.x >> 3;       // grid.x always %8==0
  int wg = (blockIdx.x & 7) * cpx + (blockIdx.x >> 3);
  int row0 = (wg & 15) * 64;      // 16 row-tiles (M=1024)
  int col0 = (wg >> 4) * 128;

  int kn = K / gridDim.y;
  int koff = blockIdx.y * kn;
  const short* Ab = A + (size_t)row0 * K + koff;
  const short* Bb = Bt + (size_t)col0 * K + koff;
  int nt = kn >> 6;

  f32x4 acc[4][2] = {};

  stage_rows<2>(Ab, K, As[0], tid);
  stage_rows<4>(Bb, K, Bs[0], tid);
  __syncthreads();

  int cur = 0;
  for (int t = 0; t < nt; ++t) {
    if (t + 1 < nt) {
      stage_rows<2>(Ab + (t + 1) * 64, K, As[cur ^ 1], tid);
      stage_rows<4>(Bb + (t + 1) * 64, K, Bs[cur ^ 1], tid);
    }
    const short* Ac = As[cur];
    const short* Bc = Bs[cur];
    #pragma unroll
    for (int kk = 0; kk < 2; ++kk) {
      short8 af[4], bf2[2];
      #pragma unroll
      for (int m = 0; m < 4; ++m)
        af[m] = frag_ld(Ac, m * 16 + l15, 4 * kk + kg);
      #pragma unroll
      for (int n = 0; n < 2; ++n)
        bf2[n] = frag_ld(Bc, wave * 32 + n * 16 + l15, 4 * kk + kg);
      #pragma unroll
      for (int m = 0; m < 4; ++m)
        #pragma unroll
        for (int n = 0; n < 2; ++n)
          acc[m][n] = __builtin_amdgcn_mfma_f32_16x16x32_bf16(af[m], bf2[n], acc[m][n], 0, 0, 0);
    }
    __syncthreads();
    cur ^= 1;
  }

  int rbase = (lane >> 4) * 4;
  if constexpr (MODE == 2) {
    int c0 = col0 + wave * 32;     // one (w1,w2) interleaved 32-col pair
    int h = (c0 >> 1) + l15;
    #pragma unroll
    for (int m = 0; m < 4; ++m) {
      #pragma unroll
      for (int r = 0; r < 4; ++r) {
        int row = row0 + m * 16 + rbase + r;
        float g1 = acc[m][0][r];
        float g2 = acc[m][1][r];
        Cs[(size_t)row * HID_DIM + h] = f2bf((g1 / (1.f + expf(-g1))) * g2);
      }
    }
  } else {
    float* Co = Cf;
    if constexpr (MODE == 1) Co += (size_t)blockIdx.y * T_SEQ * N;
    #pragma unroll
    for (int n = 0; n < 2; ++n) {
      int col = col0 + wave * 32 + n * 16 + l15;
      #pragma unroll
      for (int m = 0; m < 4; ++m) {
        #pragma unroll
        for (int r = 0; r < 4; ++r) {
          int row = row0 + m * 16 + rbase + r;
          Co[(size_t)row * N + col] = acc[m][n][r];
        }
      }
    }
  }
}

// ---------------- RACE probs with fused RoPE (vectorized loads) ------------
__global__ __launch_bounds__(256) void race_probs(const float* __restrict__ qkv,
                                                  const float* __restrict__ stc,
                                                  const float* __restrict__ planes,
                                                  float* __restrict__ pq,
                                                  float* __restrict__ pk) {
  int gid = blockIdx.x * 256 + threadIdx.x;
  int w = gid & 1;
  int l = (gid >> 1) & 3;
  int t = (gid >> 3) & 1023;
  int mn = gid >> 13;
  int m = mn / NHEAD, n = mn % NHEAD;
  const float* raw = qkv + (size_t)t * QKVW + (w ? 0 : D_MODEL) + n * 64;
  const float* sc = stc + t * 64;
  const float* pl = planes + m * 64 * 16 + l * 4;
  float p0 = 0.f, p1 = 0.f, p2 = 0.f, p3 = 0.f;
  #pragma unroll 4
  for (int i = 0; i < 32; ++i) {
    float2 eo = ((const float2*)raw)[i];
    float2 cs = ((const float2*)sc)[i];
    float re = eo.x * cs.x - eo.y * cs.y;
    float ro = eo.x * cs.y + eo.y * cs.x;
    float4 pe = *(const float4*)(pl + i * 16);
    float4 po = *(const float4*)(pl + (i + 32) * 16);
    p0 += re * pe.x + ro * po.x;
    p1 += re * pe.y + ro * po.y;
    p2 += re * pe.z + ro * po.z;
    p3 += re * pe.w + ro * po.w;
  }
  float t0 = tanhf(p0) * 0.125f;
  float t1 = tanhf(p1) * 0.125f;
  float t2 = tanhf(p2) * 0.125f;
  float t3 = tanhf(p3) * 0.125f;
  float lg[16];
  float mx = -1e30f;
  #pragma unroll
  for (int r = 0; r < 16; ++r) {
    float s = ((r & 8) ? t0 : -t0) + ((r & 4) ? t1 : -t1) +
              ((r & 2) ? t2 : -t2) + ((r & 1) ? t3 : -t3);
    lg[r] = s;
    mx = fmaxf(mx, s);
  }
  float sum = 0.f;
  #pragma unroll
  for (int r = 0; r < 16; ++r) {
    float e = expf(lg[r] - mx);
    lg[r] = e;
    sum += e;
  }
  float inv = 1.f / sum;
  float* dst = (w ? pq : pk) + ((size_t)mn * T_SEQ + t) * 64 + l * 16;
  #pragma unroll
  for (int r = 0; r < 16; ++r) dst[r] = lg[r] * inv;
}

// ------ RACE pass 1: per-chunk sums (intra-wave groups, dbuf, 1 barrier) ---
__global__ __launch_bounds__(256) void race_chunksum(const float* __restrict__ pk_g,
                                                     const float* __restrict__ v_g,
                                                     float* __restrict__ csA,
                                                     float* __restrict__ csB) {
  int mn = blockIdx.x, ch = blockIdx.y;
  int n = mn % NHEAD;
  int tid = threadIdx.x;
  int wave = tid >> 6, lane = tid & 63;
  int l15 = lane & 15, g = lane >> 4;
  int d = wave * 16 + l15;
  __shared__ float L[2][2][64];   // dbuf x {pk, vv} x 64
  const float* pkrow = pk_g + ((size_t)mn * T_SEQ + (size_t)ch * TL) * 64;
  const float* vrow = v_g + (size_t)(ch * TL) * QKVW + n * 64;

  float a[16], bp[16];
  #pragma unroll
  for (int i = 0; i < 16; ++i) { a[i] = 0.f; bp[i] = 0.f; }

  float r0 = 0.f;
  if (wave == 0) r0 = pkrow[lane];
  else if (wave == 1) r0 = vrow[lane];

  int cur = 0;
  #pragma unroll 1
  for (int t = 0; t < TL; ++t) {
    if (wave < 2) L[cur][wave][lane] = r0;
    __syncthreads();
    if (t + 1 < TL) {
      if (wave == 0) r0 = pkrow[(t + 1) * 64 + lane];
      else if (wave == 1) r0 = vrow[(size_t)(t + 1) * QKVW + lane];
    }
    float vd = L[cur][1][d];
    #pragma unroll
    for (int i = 0; i < 16; ++i) {
      float p = L[cur][0][g * 16 + i];
      a[i] += p;
      bp[i] = fmaf(p, vd, bp[i]);
    }
    cur ^= 1;
  }
  size_t base = ((size_t)mn * NCH + ch) * 64;
  if (wave == 0 && l15 == 0) {
    #pragma unroll
    for (int i = 0; i < 16; ++i) csA[base + g * 16 + i] = a[i];
  }
  #pragma unroll
  for (int i = 0; i < 16; ++i) csB[(base + g * 16 + i) * 64 + d] = bp[i];
}

// ---------------- RACE pass 2: exclusive scan over chunks ----------------
__global__ __launch_bounds__(64) void race_chunkscan(float* __restrict__ csA,
                                                     float* __restrict__ csB) {
  int mn = blockIdx.x, lr = blockIdx.y;
  int d = threadIdx.x;
  float runB = 0.f, runA = 0.f;
  for (int c = 0; c < NCH; ++c) {
    size_t ib = (((size_t)mn * NCH + c) * 64 + lr) * 64 + d;
    float b = csB[ib];
    csB[ib] = runB;
    runB += b;
    if (d == 0) {
      size_t ia = ((size_t)mn * NCH + c) * 64 + lr;
      float av = csA[ia];
      csA[ia] = runA;
      runA += av;
    }
  }
}

// --- RACE pass 3: seeded scan + emit (intra-wave groups, dbuf, 1 barrier) --
__global__ __launch_bounds__(256) void race_scan_emit(const float* __restrict__ pk_g,
                                                      const float* __restrict__ pq_g,
                                                      const float* __restrict__ v_g,
                                                      const float* __restrict__ csA,
                                                      const float* __restrict__ csB,
                                                      short* __restrict__ ro) {
  int n = blockIdx.x, ch = blockIdx.y;
  int tid = threadIdx.x;
  int wave = tid >> 6, lane = tid & 63;
  int l15 = lane & 15, g = lane >> 4;
  int d = wave * 16 + l15;
  int mn0 = n, mn1 = NHEAD + n;
  __shared__ float L[2][5][64];   // dbuf x {pk0,pk1,pq0,pq1,vv} x 64

  const float* pk0r = pk_g + ((size_t)mn0 * T_SEQ + (size_t)ch * TL) * 64;
  const float* pk1r = pk_g + ((size_t)mn1 * T_SEQ + (size_t)ch * TL) * 64;
  const float* pq0r = pq_g + ((size_t)mn0 * T_SEQ + (size_t)ch * TL) * 64;
  const float* pq1r = pq_g + ((size_t)mn1 * T_SEQ + (size_t)ch * TL) * 64;
  const float* vrow = v_g + (size_t)(ch * TL) * QKVW + n * 64;
  const float* src0 = (wave == 0) ? pk0r : (wave == 1) ? pk1r
                    : (wave == 2) ? pq0r : pq1r;

  float a0[16], b0[16], a1[16], b1[16];
  size_t base0 = ((size_t)mn0 * NCH + ch) * 64;
  size_t base1 = ((size_t)mn1 * NCH + ch) * 64;
  #pragma unroll
  for (int i = 0; i < 16; ++i) {
    a0[i] = csA[base0 + g * 16 + i];
    b0[i] = csB[(base0 + g * 16 + i) * 64 + d];
    a1[i] = csA[base1 + g * 16 + i];
    b1[i] = csB[(base1 + g * 16 + i) * 64 + d];
  }

  float r0 = src0[lane];
  float r1 = (wave == 0) ? vrow[lane] : 0.f;

  int cur = 0;
  #pragma unroll 1
  for (int t = 0; t < TL; ++t) {
    L[cur][wave][lane] = r0;
    if (wave == 0) L[cur][4][lane] = r1;
    __syncthreads();
    if (t + 1 < TL) {
      r0 = src0[(t + 1) * 64 + lane];
      if (wave == 0) r1 = vrow[(size_t)(t + 1) * QKVW + lane];
    }
    float vd = L[cur][4][d];
    float c = 0.f;
    #pragma unroll
    for (int i = 0; i < 16; ++i) {
      int lr = g * 16 + i;
      float p = L[cur][0][lr];
      a0[i] += p;
      b0[i] = fmaf(p, vd, b0[i]);
      c = fmaf(L[cur][2][lr] * b0[i], __builtin_amdgcn_rcpf(a0[i] + 1e-6f), c);
      p = L[cur][1][lr];
      a1[i] += p;
      b1[i] = fmaf(p, vd, b1[i]);
      c = fmaf(L[cur][3][lr] * b1[i], __builtin_amdgcn_rcpf(a1[i] + 1e-6f), c);
    }
    c += __shfl_xor(c, 16);
    c += __shfl_xor(c, 32);
    if (g == 0)
      ro[n * (T_SEQ * 64) + (ch * TL + t) * 64 + d] = f2bf(0.5f * c);
    cur ^= 1;
  }
}

extern "C" void kernel_launch(void* const* d_in, const int* in_sizes, int n_in,
                              void* d_out, int out_size, void* d_ws, size_t ws_size,
                              hipStream_t stream) {
  const int*   in_idx       = (const int*)d_in[0];
  const float* tok_emb      = (const float*)d_in[1];
  const float* norm1_w      = (const float*)d_in[2];
  const float* qw           = (const float*)d_in[3];
  const float* kw           = (const float*)d_in[4];
  const float* vw           = (const float*)d_in[5];
  const float* ow           = (const float*)d_in[6];
  const float* ob           = (const float*)d_in[7];
  const float* norm2_w      = (const float*)d_in[8];
  const float* ff_w1        = (const float*)d_in[9];
  const float* ff_w2        = (const float*)d_in[10];
  const float* ff_w3        = (const float*)d_in[11];
  const float* final_norm_w = (const float*)d_in[12];
  const float* out_w        = (const float*)d_in[13];
  const float* planes       = (const float*)d_in[14];

  float* ws = (float*)d_ws;
  const size_t SZ_TD = (size_t)T_SEQ * D_MODEL;
  float* X   = ws;
  float* STC = X + SZ_TD;
  float* S   = STC + 65536;
  short* HbB = (short*)S;                                // 393216 f
  float* QKV = S + 393216;                               // 2359296 f
  float* PK  = QKV + (size_t)T_SEQ * QKVW;               // 1572864 f
  float* PQ  = PK + (size_t)MCOPY * NHEAD * T_SEQ * 64;  // 1572864 f
  float* CSA = PQ + (size_t)MCOPY * NHEAD * T_SEQ * 64;  // 49152 f
  float* CSB = CSA + (size_t)MCOPY * NHEAD * NCH * 64;   // 3145728 f
  short* ROb = (short*)(CSB + (size_t)MCOPY * NHEAD * NCH * 64 * 64);
  short* G1B = (short*)QKV;                              // FF12 out alias
  float* PP  = PK;                                       // split-K partials alias
  short* WB = (short*)(S + 9486336);
  short* outT = WB + NLAYER * LAYER_W;

  stc_k<<<T_SEQ, 64, 0, stream>>>(STC);
  dim3 tb(32, 8);
  transpose_sq8<<<dim3(24, 24, 8), tb, 0, stream>>>(qw, kw, vw, ow, WB);
  transpose_ff12<<<dim3(192, 24, 2), tb, 0, stream>>>(ff_w1, ff_w2, WB);
  transpose_f3<<<dim3(24, 96, 2), tb, 0, stream>>>(ff_w3, WB);
  transpose_head<<<dim3(1000, 24), tb, 0, stream>>>(out_w, outT);

  embed_norm_k<<<T_SEQ, 256, 0, stream>>>(in_idx, tok_emb, norm1_w, X, HbB);

  for (int l = 0; l < NLAYER; ++l) {
    short* base = WB + (size_t)l * LAYER_W;
    short* qkvT = base;
    short* owT  = base + 3 * SQ_W;
    short* f12T = base + 4 * SQ_W;
    short* f3T  = base + 4 * SQ_W + 2 * FF_W;

    gemm64<0><<<dim3(16 * (QKVW / 128), 1), 256, 0, stream>>>(HbB, qkvT, QKV, nullptr, QKVW, D_MODEL);
    race_probs<<<(MCOPY * NHEAD * T_SEQ * 4 * 2) / 256, 256, 0, stream>>>(
        QKV, STC, planes + (size_t)l * MCOPY * 64 * 16, PQ, PK);
    dim3 gps(MCOPY * NHEAD, NCH);
    race_chunksum<<<gps, 256, 0, stream>>>(PK, QKV + 2 * D_MODEL, CSA, CSB);
    dim3 gcs(MCOPY * NHEAD, 64);
    race_chunkscan<<<gcs, 64, 0, stream>>>(CSA, CSB);
    dim3 gemit(NHEAD, NCH);
    race_scan_emit<<<gemit, 256, 0, stream>>>(PK, PQ, QKV + 2 * D_MODEL, CSA, CSB, ROb);
    // O-proj: split-K=2 (round-12 proven config)
    gemm64<1><<<dim3(16 * (D_MODEL / 128), 2), 256, 0, stream>>>(ROb, owT, PP, nullptr, D_MODEL, D_MODEL);
    add_norm_k<<<T_SEQ, 256, 0, stream>>>(X, PP, 2, ob + l * D_MODEL, norm2_w + l * D_MODEL, HbB);
    // FF12 fused silu via gemm64 MODE 2 (768 blocks, 3/CU exact)
    gemm64<2><<<dim3(16 * (2 * HID_DIM / 128), 1), 256, 0, stream>>>(HbB, f12T, nullptr, G1B, 2 * HID_DIM, D_MODEL);
    // FF3: split-K=4 (round-12 proven config)
    gemm64<1><<<dim3(16 * (D_MODEL / 128), 4), 256, 0, stream>>>(G1B, f3T, PP, nullptr, D_MODEL, HID_DIM);
    const float* nw = (l == NLAYER - 1) ? final_norm_w : norm1_w + (l + 1) * D_MODEL;
    add_norm_k<<<T_SEQ, 256, 0, stream>>>(X, PP, 4, nullptr, nw, HbB);
  }
  // head GEMM via gemm64 structure: 4000 blocks, dbuf, 3 blocks/CU
  gemm64<0><<<dim3(16 * (VSIZE / 128), 1), 256, 0, stream>>>(HbB, outT, (float*)d_out, nullptr, VSIZE, D_MODEL);
}

// Round 15
// 458.784 us; speedup vs baseline: 1.0523x; 1.0523x over previous
//
#include <hip/hip_runtime.h>
#include <hip/hip_bf16.h>

#define T_SEQ 1024
#define D_MODEL 768
#define QKVW 2304
#define NHEAD 12
#define NLAYER 2
#define MCOPY 2
#define HID_DIM 3072
#define VSIZE 32000
#define NCH 32
#define TL 32

typedef __attribute__((ext_vector_type(8))) short short8;
typedef __attribute__((ext_vector_type(4))) float f32x4;

__device__ __forceinline__ short f2bf(float f) {
  unsigned u = __builtin_bit_cast(unsigned, f);
  u = (u + 0x7FFFu + ((u >> 16) & 1u)) >> 16;   // RNE
  return (short)u;
}

// ---------------- sin/cos table: stc[t][i] = (cos, sin) ----------------
__global__ __launch_bounds__(64) void stc_k(float* __restrict__ stc) {
  int t = blockIdx.x;
  int i = threadIdx.x;
  if (i < 32) {
    float theta = powf(10000.0f, -(float)i / 32.0f);
    float s, c;
    sincosf((float)t * theta, &s, &c);
    stc[t * 64 + 2 * i] = c;
    stc[t * 64 + 2 * i + 1] = s;
  }
}

// -------- fused embedding gather + rmsnorm -> X (f32) and HbB (bf16) -------
__global__ __launch_bounds__(256) void embed_norm_k(const int* __restrict__ idx,
                                                    const float* __restrict__ emb,
                                                    const float* __restrict__ w,
                                                    float* __restrict__ x,
                                                    short* __restrict__ out) {
  int t = blockIdx.x, tid = threadIdx.x;
  int r = idx[t];
  float v[3];
  float ss = 0.f;
  #pragma unroll
  for (int j = 0; j < 3; ++j) {
    int i = tid + j * 256;
    float val = emb[(size_t)r * D_MODEL + i];
    x[(size_t)t * D_MODEL + i] = val;
    v[j] = val;
    ss += val * val;
  }
  __shared__ float red[256];
  red[tid] = ss; __syncthreads();
  for (int s = 128; s > 0; s >>= 1) {
    if (tid < s) red[tid] += red[tid + s];
    __syncthreads();
  }
  float inv = rsqrtf(red[0] / (float)D_MODEL + 1e-5f);
  #pragma unroll
  for (int j = 0; j < 3; ++j) {
    int i = tid + j * 256;
    out[(size_t)t * D_MODEL + i] = f2bf(v[j] * inv * w[i]);
  }
}

// ------- fused: X += sum(parts) (+bias); out = rmsnorm(X)*w -> bf16 -------
__global__ __launch_bounds__(256) void add_norm_k(float* __restrict__ x,
                                                  const float* __restrict__ parts,
                                                  int nparts,
                                                  const float* __restrict__ bias,
                                                  const float* __restrict__ w,
                                                  short* __restrict__ out) {
  int t = blockIdx.x, tid = threadIdx.x;
  float v[3];
  float ss = 0.f;
  #pragma unroll
  for (int j = 0; j < 3; ++j) {
    int i = tid + j * 256;
    float val = x[(size_t)t * D_MODEL + i];
    if (bias) val += bias[i];
    for (int p = 0; p < nparts; ++p)
      val += parts[(size_t)p * (T_SEQ * D_MODEL) + (size_t)t * D_MODEL + i];
    v[j] = val;
    ss += val * val;
  }
  __shared__ float red[256];
  red[tid] = ss; __syncthreads();
  for (int s = 128; s > 0; s >>= 1) {
    if (tid < s) red[tid] += red[tid + s];
    __syncthreads();
  }
  float inv = rsqrtf(red[0] / (float)D_MODEL + 1e-5f);
  #pragma unroll
  for (int j = 0; j < 3; ++j) {
    int i = tid + j * 256;
    if (nparts || bias) x[(size_t)t * D_MODEL + i] = v[j];
    out[(size_t)t * D_MODEL + i] = f2bf(v[j] * inv * w[i]);
  }
}

// ------------- batched weight transposes (f32 [K][N] -> bf16 [N][K]) -------
__device__ __forceinline__ void tr_tile(const float* __restrict__ W,
                                        short* __restrict__ WT, int K, int N,
                                        int n0, int k0, int tx, int ty) {
  __shared__ float tile[32][33];
  #pragma unroll
  for (int i = 0; i < 4; ++i)
    tile[ty + 8 * i][tx] = W[(size_t)(k0 + ty + 8 * i) * N + n0 + tx];
  __syncthreads();
  #pragma unroll
  for (int i = 0; i < 4; ++i)
    WT[(size_t)(n0 + ty + 8 * i) * K + k0 + tx] = f2bf(tile[tx][ty + 8 * i]);
}

#define SQ_W  ((size_t)D_MODEL * D_MODEL)
#define FF_W  ((size_t)D_MODEL * HID_DIM)
#define LAYER_W (4 * SQ_W + 3 * FF_W)

__global__ __launch_bounds__(256) void transpose_sq8(const float* __restrict__ qw,
                                                     const float* __restrict__ kw,
                                                     const float* __restrict__ vw,
                                                     const float* __restrict__ ow,
                                                     short* __restrict__ WB) {
  int z = blockIdx.z, layer = z >> 2, which = z & 3;
  const float* W = (which == 0) ? qw : (which == 1) ? kw : (which == 2) ? vw : ow;
  W += (size_t)layer * SQ_W;
  short* WT = WB + (size_t)layer * LAYER_W + (size_t)which * SQ_W;
  tr_tile(W, WT, D_MODEL, D_MODEL, blockIdx.x * 32, blockIdx.y * 32,
          threadIdx.x, threadIdx.y);
}

__global__ __launch_bounds__(256) void transpose_ff12(const float* __restrict__ W1g,
                                                      const float* __restrict__ W2g,
                                                      short* __restrict__ WB) {
  __shared__ float tile[32][33];
  int layer = blockIdx.z;
  const float* W1 = W1g + (size_t)layer * FF_W;
  const float* W2 = W2g + (size_t)layer * FF_W;
  short* WT = WB + (size_t)layer * LAYER_W + 4 * SQ_W;
  int tx = threadIdx.x, ty = threadIdx.y;
  int n0 = blockIdx.x * 32, k0 = blockIdx.y * 32;
  int h0 = n0 >> 1;
  const float* src = (tx < 16) ? (W1 + h0 + tx) : (W2 + h0 + (tx - 16));
  #pragma unroll
  for (int i = 0; i < 4; ++i)
    tile[ty + 8 * i][tx] = src[(size_t)(k0 + ty + 8 * i) * HID_DIM];
  __syncthreads();
  #pragma unroll
  for (int i = 0; i < 4; ++i) {
    int n = ty + 8 * i;
    WT[(size_t)(n0 + n) * D_MODEL + k0 + tx] = f2bf(tile[tx][n]);
  }
}

__global__ __launch_bounds__(256) void transpose_f3(const float* __restrict__ W3g,
                                                    short* __restrict__ WB) {
  int layer = blockIdx.z;
  const float* W = W3g + (size_t)layer * FF_W;
  short* WT = WB + (size_t)layer * LAYER_W + 4 * SQ_W + 2 * FF_W;
  tr_tile(W, WT, HID_DIM, D_MODEL, blockIdx.x * 32, blockIdx.y * 32,
          threadIdx.x, threadIdx.y);
}

__global__ __launch_bounds__(256) void transpose_head(const float* __restrict__ W,
                                                      short* __restrict__ WT) {
  tr_tile(W, WT, D_MODEL, VSIZE, blockIdx.x * 32, blockIdx.y * 32,
          threadIdx.x, threadIdx.y);
}

// ---------------- staging helper: NROW32*32 rows x 64 k (bf16) -------------
template<int NROW32>
__device__ __forceinline__ void stage_rows(const short* __restrict__ gbase,
                                           int ldK, short* lds, int tid) {
  #pragma unroll
  for (int j = 0; j < NROW32; ++j) {
    int r = j * 32 + (tid >> 3);
    int s = tid & 7;
    const short* gp = gbase + (size_t)r * ldK + (((s ^ (r & 7))) << 3);
    short* lp = lds + j * 2048 + tid * 8;
    __builtin_amdgcn_global_load_lds((const __attribute__((address_space(1))) void*)gp,
                                     (__attribute__((address_space(3))) void*)lp,
                                     16, 0, 0);
  }
}

__device__ __forceinline__ short8 frag_ld(const short* lds, int row, int sl) {
  return *(const short8*)(lds + row * 64 + ((sl ^ (row & 7)) << 3));
}

// ---------- gemm_t: 128x128 single-buffered (head; proven 80 µs) ----------
template<int MODE, int DBUF>
__global__ __launch_bounds__(256) void gemm_t(const short* __restrict__ A,
                                              const short* __restrict__ Bt,
                                              float* __restrict__ Cf,
                                              short* __restrict__ Cs,
                                              int N, int K) {
  __shared__ short As[DBUF + 1][128 * 64];
  __shared__ short Bs[DBUF + 1][128 * 64];
  int tid = threadIdx.x;
  int lane = tid & 63;
  int wave = tid >> 6;
  int wr = wave >> 1, wc = wave & 1;
  int l15 = lane & 15, kg = lane >> 4;

  int cpx = gridDim.x >> 3;
  int wg = (blockIdx.x & 7) * cpx + (blockIdx.x >> 3);
  int row0 = (wg & 7) * 128;
  int col0 = (wg >> 3) * 128;

  int kn = K / gridDim.y;
  int koff = blockIdx.y * kn;
  const short* Ab = A + (size_t)row0 * K + koff;
  const short* Bb = Bt + (size_t)col0 * K + koff;
  int nt = kn >> 6;

  f32x4 acc[4][4] = {};

  if constexpr (DBUF) {
    stage_rows<4>(Ab, K, As[0], tid);
    stage_rows<4>(Bb, K, Bs[0], tid);
    __syncthreads();
  }

  int cur = 0;
  for (int t = 0; t < nt; ++t) {
    if constexpr (DBUF) {
      if (t + 1 < nt) {
        stage_rows<4>(Ab + (t + 1) * 64, K, As[cur ^ 1], tid);
        stage_rows<4>(Bb + (t + 1) * 64, K, Bs[cur ^ 1], tid);
      }
    } else {
      stage_rows<4>(Ab + t * 64, K, As[0], tid);
      stage_rows<4>(Bb + t * 64, K, Bs[0], tid);
      __syncthreads();
    }
    const short* Ac = As[cur];
    const short* Bc = Bs[cur];
    #pragma unroll
    for (int kk = 0; kk < 2; ++kk) {
      short8 af[4], bf4[4];
      #pragma unroll
      for (int m = 0; m < 4; ++m)
        af[m] = frag_ld(Ac, wr * 64 + m * 16 + l15, 4 * kk + kg);
      #pragma unroll
      for (int n = 0; n < 4; ++n)
        bf4[n] = frag_ld(Bc, wc * 64 + n * 16 + l15, 4 * kk + kg);
      #pragma unroll
      for (int m = 0; m < 4; ++m)
        #pragma unroll
        for (int n = 0; n < 4; ++n)
          acc[m][n] = __builtin_amdgcn_mfma_f32_16x16x32_bf16(af[m], bf4[n], acc[m][n], 0, 0, 0);
    }
    __syncthreads();
    if constexpr (DBUF) cur ^= 1;
  }

  int rbase = (lane >> 4) * 4;
  float* Co = Cf;
  if constexpr (MODE == 1) Co += (size_t)blockIdx.y * T_SEQ * N;
  #pragma unroll
  for (int n = 0; n < 4; ++n) {
    int col = col0 + wc * 64 + n * 16 + l15;
    #pragma unroll
    for (int m = 0; m < 4; ++m) {
      #pragma unroll
      for (int r = 0; r < 4; ++r) {
        int row = row0 + wr * 64 + m * 16 + rbase + r;
        Co[(size_t)row * N + col] = acc[m][n][r];
      }
    }
  }
}

// ------ gemm64: 64x128 tile, dbuf; MODE 0/1 f32 out, MODE 2 silu-bf16 ------
// Latency-bound small GEMMs only (QKV/O/FF) — loses on head (r14 measured).
template<int MODE>
__global__ __launch_bounds__(256) void gemm64(const short* __restrict__ A,
                                              const short* __restrict__ Bt,
                                              float* __restrict__ Cf,
                                              short* __restrict__ Cs,
                                              int N, int K) {
  __shared__ short As[2][64 * 64];
  __shared__ short Bs[2][128 * 64];
  int tid = threadIdx.x;
  int lane = tid & 63;
  int wave = tid >> 6;            // col section
  int l15 = lane & 15, kg = lane >> 4;

  int cpx = gridDim.x >> 3;       // grid.x always %8==0
  int wg = (blockIdx.x & 7) * cpx + (blockIdx.x >> 3);
  int row0 = (wg & 15) * 64;      // 16 row-tiles (M=1024)
  int col0 = (wg >> 4) * 128;

  int kn = K / gridDim.y;
  int koff = blockIdx.y * kn;
  const short* Ab = A + (size_t)row0 * K + koff;
  const short* Bb = Bt + (size_t)col0 * K + koff;
  int nt = kn >> 6;

  f32x4 acc[4][2] = {};

  stage_rows<2>(Ab, K, As[0], tid);
  stage_rows<4>(Bb, K, Bs[0], tid);
  __syncthreads();

  int cur = 0;
  for (int t = 0; t < nt; ++t) {
    if (t + 1 < nt) {
      stage_rows<2>(Ab + (t + 1) * 64, K, As[cur ^ 1], tid);
      stage_rows<4>(Bb + (t + 1) * 64, K, Bs[cur ^ 1], tid);
    }
    const short* Ac = As[cur];
    const short* Bc = Bs[cur];
    #pragma unroll
    for (int kk = 0; kk < 2; ++kk) {
      short8 af[4], bf2[2];
      #pragma unroll
      for (int m = 0; m < 4; ++m)
        af[m] = frag_ld(Ac, m * 16 + l15, 4 * kk + kg);
      #pragma unroll
      for (int n = 0; n < 2; ++n)
        bf2[n] = frag_ld(Bc, wave * 32 + n * 16 + l15, 4 * kk + kg);
      #pragma unroll
      for (int m = 0; m < 4; ++m)
        #pragma unroll
        for (int n = 0; n < 2; ++n)
          acc[m][n] = __builtin_amdgcn_mfma_f32_16x16x32_bf16(af[m], bf2[n], acc[m][n], 0, 0, 0);
    }
    __syncthreads();
    cur ^= 1;
  }

  int rbase = (lane >> 4) * 4;
  if constexpr (MODE == 2) {
    int c0 = col0 + wave * 32;     // one (w1,w2) interleaved 32-col pair
    int h = (c0 >> 1) + l15;
    #pragma unroll
    for (int m = 0; m < 4; ++m) {
      #pragma unroll
      for (int r = 0; r < 4; ++r) {
        int row = row0 + m * 16 + rbase + r;
        float g1 = acc[m][0][r];
        float g2 = acc[m][1][r];
        Cs[(size_t)row * HID_DIM + h] = f2bf((g1 / (1.f + expf(-g1))) * g2);
      }
    }
  } else {
    float* Co = Cf;
    if constexpr (MODE == 1) Co += (size_t)blockIdx.y * T_SEQ * N;
    #pragma unroll
    for (int n = 0; n < 2; ++n) {
      int col = col0 + wave * 32 + n * 16 + l15;
      #pragma unroll
      for (int m = 0; m < 4; ++m) {
        #pragma unroll
        for (int r = 0; r < 4; ++r) {
          int row = row0 + m * 16 + rbase + r;
          Co[(size_t)row * N + col] = acc[m][n][r];
        }
      }
    }
  }
}

// ---------------- RACE probs with fused RoPE (vectorized loads) ------------
__global__ __launch_bounds__(256) void race_probs(const float* __restrict__ qkv,
                                                  const float* __restrict__ stc,
                                                  const float* __restrict__ planes,
                                                  float* __restrict__ pq,
                                                  float* __restrict__ pk) {
  int gid = blockIdx.x * 256 + threadIdx.x;
  int w = gid & 1;
  int l = (gid >> 1) & 3;
  int t = (gid >> 3) & 1023;
  int mn = gid >> 13;
  int m = mn / NHEAD, n = mn % NHEAD;
  const float* raw = qkv + (size_t)t * QKVW + (w ? 0 : D_MODEL) + n * 64;
  const float* sc = stc + t * 64;
  const float* pl = planes + m * 64 * 16 + l * 4;
  float p0 = 0.f, p1 = 0.f, p2 = 0.f, p3 = 0.f;
  #pragma unroll 4
  for (int i = 0; i < 32; ++i) {
    float2 eo = ((const float2*)raw)[i];
    float2 cs = ((const float2*)sc)[i];
    float re = eo.x * cs.x - eo.y * cs.y;
    float ro = eo.x * cs.y + eo.y * cs.x;
    float4 pe = *(const float4*)(pl + i * 16);
    float4 po = *(const float4*)(pl + (i + 32) * 16);
    p0 += re * pe.x + ro * po.x;
    p1 += re * pe.y + ro * po.y;
    p2 += re * pe.z + ro * po.z;
    p3 += re * pe.w + ro * po.w;
  }
  float t0 = tanhf(p0) * 0.125f;
  float t1 = tanhf(p1) * 0.125f;
  float t2 = tanhf(p2) * 0.125f;
  float t3 = tanhf(p3) * 0.125f;
  float lg[16];
  float mx = -1e30f;
  #pragma unroll
  for (int r = 0; r < 16; ++r) {
    float s = ((r & 8) ? t0 : -t0) + ((r & 4) ? t1 : -t1) +
              ((r & 2) ? t2 : -t2) + ((r & 1) ? t3 : -t3);
    lg[r] = s;
    mx = fmaxf(mx, s);
  }
  float sum = 0.f;
  #pragma unroll
  for (int r = 0; r < 16; ++r) {
    float e = expf(lg[r] - mx);
    lg[r] = e;
    sum += e;
  }
  float inv = 1.f / sum;
  float* dst = (w ? pq : pk) + ((size_t)mn * T_SEQ + t) * 64 + l * 16;
  #pragma unroll
  for (int r = 0; r < 16; ++r) dst[r] = lg[r] * inv;
}

// ------ RACE pass 1: per-chunk sums (intra-wave groups, dbuf, 1 barrier) ---
__global__ __launch_bounds__(256) void race_chunksum(const float* __restrict__ pk_g,
                                                     const float* __restrict__ v_g,
                                                     float* __restrict__ csA,
                                                     float* __restrict__ csB) {
  int mn = blockIdx.x, ch = blockIdx.y;
  int n = mn % NHEAD;
  int tid = threadIdx.x;
  int wave = tid >> 6, lane = tid & 63;
  int l15 = lane & 15, g = lane >> 4;
  int d = wave * 16 + l15;
  __shared__ float L[2][2][64];   // dbuf x {pk, vv} x 64
  const float* pkrow = pk_g + ((size_t)mn * T_SEQ + (size_t)ch * TL) * 64;
  const float* vrow = v_g + (size_t)(ch * TL) * QKVW + n * 64;

  float a[16], bp[16];
  #pragma unroll
  for (int i = 0; i < 16; ++i) { a[i] = 0.f; bp[i] = 0.f; }

  float r0 = 0.f;
  if (wave == 0) r0 = pkrow[lane];
  else if (wave == 1) r0 = vrow[lane];

  int cur = 0;
  #pragma unroll 1
  for (int t = 0; t < TL; ++t) {
    if (wave < 2) L[cur][wave][lane] = r0;
    __syncthreads();
    if (t + 1 < TL) {
      if (wave == 0) r0 = pkrow[(t + 1) * 64 + lane];
      else if (wave == 1) r0 = vrow[(size_t)(t + 1) * QKVW + lane];
    }
    float vd = L[cur][1][d];
    #pragma unroll
    for (int i = 0; i < 16; ++i) {
      float p = L[cur][0][g * 16 + i];
      a[i] += p;
      bp[i] = fmaf(p, vd, bp[i]);
    }
    cur ^= 1;
  }
  size_t base = ((size_t)mn * NCH + ch) * 64;
  if (wave == 0 && l15 == 0) {
    #pragma unroll
    for (int i = 0; i < 16; ++i) csA[base + g * 16 + i] = a[i];
  }
  #pragma unroll
  for (int i = 0; i < 16; ++i) csB[(base + g * 16 + i) * 64 + d] = bp[i];
}

// ---------------- RACE pass 2: exclusive scan over chunks ----------------
__global__ __launch_bounds__(64) void race_chunkscan(float* __restrict__ csA,
                                                     float* __restrict__ csB) {
  int mn = blockIdx.x, lr = blockIdx.y;
  int d = threadIdx.x;
  float runB = 0.f, runA = 0.f;
  for (int c = 0; c < NCH; ++c) {
    size_t ib = (((size_t)mn * NCH + c) * 64 + lr) * 64 + d;
    float b = csB[ib];
    csB[ib] = runB;
    runB += b;
    if (d == 0) {
      size_t ia = ((size_t)mn * NCH + c) * 64 + lr;
      float av = csA[ia];
      csA[ia] = runA;
      runA += av;
    }
  }
}

// --- RACE pass 3: seeded scan + emit (intra-wave groups, dbuf, 1 barrier) --
__global__ __launch_bounds__(256) void race_scan_emit(const float* __restrict__ pk_g,
                                                      const float* __restrict__ pq_g,
                                                      const float* __restrict__ v_g,
                                                      const float* __restrict__ csA,
                                                      const float* __restrict__ csB,
                                                      short* __restrict__ ro) {
  int n = blockIdx.x, ch = blockIdx.y;
  int tid = threadIdx.x;
  int wave = tid >> 6, lane = tid & 63;
  int l15 = lane & 15, g = lane >> 4;
  int d = wave * 16 + l15;
  int mn0 = n, mn1 = NHEAD + n;
  __shared__ float L[2][5][64];   // dbuf x {pk0,pk1,pq0,pq1,vv} x 64

  const float* pk0r = pk_g + ((size_t)mn0 * T_SEQ + (size_t)ch * TL) * 64;
  const float* pk1r = pk_g + ((size_t)mn1 * T_SEQ + (size_t)ch * TL) * 64;
  const float* pq0r = pq_g + ((size_t)mn0 * T_SEQ + (size_t)ch * TL) * 64;
  const float* pq1r = pq_g + ((size_t)mn1 * T_SEQ + (size_t)ch * TL) * 64;
  const float* vrow = v_g + (size_t)(ch * TL) * QKVW + n * 64;
  const float* src0 = (wave == 0) ? pk0r : (wave == 1) ? pk1r
                    : (wave == 2) ? pq0r : pq1r;

  float a0[16], b0[16], a1[16], b1[16];
  size_t base0 = ((size_t)mn0 * NCH + ch) * 64;
  size_t base1 = ((size_t)mn1 * NCH + ch) * 64;
  #pragma unroll
  for (int i = 0; i < 16; ++i) {
    a0[i] = csA[base0 + g * 16 + i];
    b0[i] = csB[(base0 + g * 16 + i) * 64 + d];
    a1[i] = csA[base1 + g * 16 + i];
    b1[i] = csB[(base1 + g * 16 + i) * 64 + d];
  }

  float r0 = src0[lane];
  float r1 = (wave == 0) ? vrow[lane] : 0.f;

  int cur = 0;
  #pragma unroll 1
  for (int t = 0; t < TL; ++t) {
    L[cur][wave][lane] = r0;
    if (wave == 0) L[cur][4][lane] = r1;
    __syncthreads();
    if (t + 1 < TL) {
      r0 = src0[(t + 1) * 64 + lane];
      if (wave == 0) r1 = vrow[(size_t)(t + 1) * QKVW + lane];
    }
    float vd = L[cur][4][d];
    float c = 0.f;
    #pragma unroll
    for (int i = 0; i < 16; ++i) {
      int lr = g * 16 + i;
      float p = L[cur][0][lr];
      a0[i] += p;
      b0[i] = fmaf(p, vd, b0[i]);
      c = fmaf(L[cur][2][lr] * b0[i], __builtin_amdgcn_rcpf(a0[i] + 1e-6f), c);
      p = L[cur][1][lr];
      a1[i] += p;
      b1[i] = fmaf(p, vd, b1[i]);
      c = fmaf(L[cur][3][lr] * b1[i], __builtin_amdgcn_rcpf(a1[i] + 1e-6f), c);
    }
    c += __shfl_xor(c, 16);
    c += __shfl_xor(c, 32);
    if (g == 0)
      ro[n * (T_SEQ * 64) + (ch * TL + t) * 64 + d] = f2bf(0.5f * c);
    cur ^= 1;
  }
}

extern "C" void kernel_launch(void* const* d_in, const int* in_sizes, int n_in,
                              void* d_out, int out_size, void* d_ws, size_t ws_size,
                              hipStream_t stream) {
  const int*   in_idx       = (const int*)d_in[0];
  const float* tok_emb      = (const float*)d_in[1];
  const float* norm1_w      = (const float*)d_in[2];
  const float* qw           = (const float*)d_in[3];
  const float* kw           = (const float*)d_in[4];
  const float* vw           = (const float*)d_in[5];
  const float* ow           = (const float*)d_in[6];
  const float* ob           = (const float*)d_in[7];
  const float* norm2_w      = (const float*)d_in[8];
  const float* ff_w1        = (const float*)d_in[9];
  const float* ff_w2        = (const float*)d_in[10];
  const float* ff_w3        = (const float*)d_in[11];
  const float* final_norm_w = (const float*)d_in[12];
  const float* out_w        = (const float*)d_in[13];
  const float* planes       = (const float*)d_in[14];

  float* ws = (float*)d_ws;
  const size_t SZ_TD = (size_t)T_SEQ * D_MODEL;
  float* X   = ws;
  float* STC = X + SZ_TD;
  float* S   = STC + 65536;
  short* HbB = (short*)S;                                // 393216 f
  float* QKV = S + 393216;                               // 2359296 f
  float* PK  = QKV + (size_t)T_SEQ * QKVW;               // 1572864 f
  float* PQ  = PK + (size_t)MCOPY * NHEAD * T_SEQ * 64;  // 1572864 f
  float* CSA = PQ + (size_t)MCOPY * NHEAD * T_SEQ * 64;  // 49152 f
  float* CSB = CSA + (size_t)MCOPY * NHEAD * NCH * 64;   // 3145728 f
  short* ROb = (short*)(CSB + (size_t)MCOPY * NHEAD * NCH * 64 * 64);
  short* G1B = (short*)QKV;                              // FF12 out alias
  float* PP  = PK;                                       // split-K partials alias
  short* WB = (short*)(S + 9486336);
  short* outT = WB + NLAYER * LAYER_W;

  stc_k<<<T_SEQ, 64, 0, stream>>>(STC);
  dim3 tb(32, 8);
  transpose_sq8<<<dim3(24, 24, 8), tb, 0, stream>>>(qw, kw, vw, ow, WB);
  transpose_ff12<<<dim3(192, 24, 2), tb, 0, stream>>>(ff_w1, ff_w2, WB);
  transpose_f3<<<dim3(24, 96, 2), tb, 0, stream>>>(ff_w3, WB);
  transpose_head<<<dim3(1000, 24), tb, 0, stream>>>(out_w, outT);

  embed_norm_k<<<T_SEQ, 256, 0, stream>>>(in_idx, tok_emb, norm1_w, X, HbB);

  for (int l = 0; l < NLAYER; ++l) {
    short* base = WB + (size_t)l * LAYER_W;
    short* qkvT = base;
    short* owT  = base + 3 * SQ_W;
    short* f12T = base + 4 * SQ_W;
    short* f3T  = base + 4 * SQ_W + 2 * FF_W;

    gemm64<0><<<dim3(16 * (QKVW / 128), 1), 256, 0, stream>>>(HbB, qkvT, QKV, nullptr, QKVW, D_MODEL);
    race_probs<<<(MCOPY * NHEAD * T_SEQ * 4 * 2) / 256, 256, 0, stream>>>(
        QKV, STC, planes + (size_t)l * MCOPY * 64 * 16, PQ, PK);
    dim3 gps(MCOPY * NHEAD, NCH);
    race_chunksum<<<gps, 256, 0, stream>>>(PK, QKV + 2 * D_MODEL, CSA, CSB);
    dim3 gcs(MCOPY * NHEAD, 64);
    race_chunkscan<<<gcs, 64, 0, stream>>>(CSA, CSB);
    dim3 gemit(NHEAD, NCH);
    race_scan_emit<<<gemit, 256, 0, stream>>>(PK, PQ, QKV + 2 * D_MODEL, CSA, CSB, ROb);
    // O-proj: split-K=2
    gemm64<1><<<dim3(16 * (D_MODEL / 128), 2), 256, 0, stream>>>(ROb, owT, PP, nullptr, D_MODEL, D_MODEL);
    add_norm_k<<<T_SEQ, 256, 0, stream>>>(X, PP, 2, ob + l * D_MODEL, norm2_w + l * D_MODEL, HbB);
    // FF12 fused silu via gemm64 MODE 2
    gemm64<2><<<dim3(16 * (2 * HID_DIM / 128), 1), 256, 0, stream>>>(HbB, f12T, nullptr, G1B, 2 * HID_DIM, D_MODEL);
    // FF3: split-K=4
    gemm64<1><<<dim3(16 * (D_MODEL / 128), 4), 256, 0, stream>>>(G1B, f3T, PP, nullptr, D_MODEL, HID_DIM);
    const float* nw = (l == NLAYER - 1) ? final_norm_w : norm1_w + (l + 1) * D_MODEL;
    add_norm_k<<<T_SEQ, 256, 0, stream>>>(X, PP, 4, nullptr, nw, HbB);
  }
  // head GEMM: 128x128 single-buffered (proven fastest at this shape)
  gemm_t<0, 0><<<dim3(8 * (VSIZE / 128), 1), 256, 0, stream>>>(HbB, outT, (float*)d_out, nullptr, VSIZE, D_MODEL);
}